// Round 1
// baseline (250.799 us; speedup 1.0000x reference)
//
#include <hip/hip_runtime.h>
#include <hip/hip_bf16.h>

#define B_DIM 16
#define C_DIM 512
#define HW_DIM 4096
#define LN_EPS 1e-5f

using bf16 = __hip_bfloat16;
typedef __bf16 v8bf __attribute__((ext_vector_type(8)));
typedef float v4f __attribute__((ext_vector_type(4)));
typedef unsigned short v8us __attribute__((ext_vector_type(8)));
using gptr_t = const __attribute__((address_space(1))) void*;
using lptr_t = __attribute__((address_space(3))) void*;

__device__ __forceinline__ unsigned short f2bf(float f) {
  unsigned int u = __float_as_uint(f);
  u = (u + 0x7fffu + ((u >> 16) & 1u)) >> 16;  // RNE
  return (unsigned short)u;
}
__device__ __forceinline__ float bf2f(unsigned short us) {
  return __uint_as_float(((unsigned int)us) << 16);
}

// ---------------- pass 0: f32 -> bf16 (V) and bf16 transposed (VT) ----------
// 64(hw) x 64(c) tile per block; 16B loads, 16B stores on both outputs.
__global__ __launch_bounds__(256) void k_convert_transpose(
    const float* __restrict__ x, unsigned short* __restrict__ v,
    unsigned short* __restrict__ vt) {
  __shared__ unsigned short tile[64][66];  // [c][hw], pad 66 (33-dword stride)
  const int tid = threadIdx.x;
  const int b = blockIdx.z;
  const int n0 = blockIdx.x * 64;
  const int c0 = blockIdx.y * 64;
  const size_t boff = (size_t)b * ((size_t)C_DIM * HW_DIM);
  const float* xb = x + boff;
  unsigned short* vb = v + boff;
  unsigned short* vtb = vt + boff;

  const int cl = tid >> 3;           // 0..31
  const int h8 = (tid & 7) * 8;      // 0,8,..56
#pragma unroll
  for (int j = 0; j < 2; ++j) {
    const int c = cl + j * 32;
    const float* src = xb + (size_t)(c0 + c) * HW_DIM + n0 + h8;
    const float4 f0 = ((const float4*)src)[0];
    const float4 f1 = ((const float4*)src)[1];
    v8us pack;
    pack[0] = f2bf(f0.x); pack[1] = f2bf(f0.y);
    pack[2] = f2bf(f0.z); pack[3] = f2bf(f0.w);
    pack[4] = f2bf(f1.x); pack[5] = f2bf(f1.y);
    pack[6] = f2bf(f1.z); pack[7] = f2bf(f1.w);
    *(v8us*)(vb + (size_t)(c0 + c) * HW_DIM + n0 + h8) = pack;
#pragma unroll
    for (int e = 0; e < 8; ++e) tile[c][h8 + e] = pack[e];
  }
  __syncthreads();
  const int nl = tid >> 3;           // 0..31
  const int c8 = (tid & 7) * 8;      // 0,8,..56
#pragma unroll
  for (int j = 0; j < 2; ++j) {
    const int n = nl + j * 32;
    v8us pack;
#pragma unroll
    for (int e = 0; e < 8; ++e) pack[e] = tile[c8 + e][n];
    *(v8us*)(vtb + (size_t)(n0 + n) * C_DIM + c0 + c8) = pack;
  }
}

// ---------------- shared GEMM pieces ----------------------------------------
// Tile: 128 rows x 64 k bf16, [row][k] linear in LDS (row stride 64 elems).
__device__ __forceinline__ void stage_tiles(
    const bf16* __restrict__ a_base, const bf16* __restrict__ b_base,
    const int stride, const int k0, const int wave, const int lane,
    bf16* ldsA, bf16* ldsB) {
  const int srow = lane >> 3;        // 0..7
  const int skcol = (lane & 7) * 8;  // 0..56
#pragma unroll
  for (int i = 0; i < 4; ++i) {
    const int ci = wave * 4 + i;     // chunk of 8 rows
    const int row = ci * 8 + srow;
    __builtin_amdgcn_global_load_lds(
        (gptr_t)(a_base + (size_t)row * stride + k0 + skcol),
        (lptr_t)(ldsA + ci * 512), 16, 0, 0);
    __builtin_amdgcn_global_load_lds(
        (gptr_t)(b_base + (size_t)row * stride + k0 + skcol),
        (lptr_t)(ldsB + ci * 512), 16, 0, 0);
  }
}

__device__ __forceinline__ void compute_tile(
    const bf16* ldsA, const bf16* ldsB, const int wave, const int lane,
    v4f acc[4][4]) {
  const int kb = (lane >> 4) * 8;
  const int rl = lane & 15;
  const int wr = wave >> 1, wc = wave & 1;
#pragma unroll
  for (int kk = 0; kk < 2; ++kk) {
    v8bf af[4], bfr[4];
#pragma unroll
    for (int m = 0; m < 4; ++m)
      af[m] = *(const v8bf*)(ldsA + (wr * 64 + m * 16 + rl) * 64 + kk * 32 + kb);
#pragma unroll
    for (int n = 0; n < 4; ++n)
      bfr[n] = *(const v8bf*)(ldsB + (wc * 64 + n * 16 + rl) * 64 + kk * 32 + kb);
#pragma unroll
    for (int m = 0; m < 4; ++m)
#pragma unroll
      for (int n = 0; n < 4; ++n)
        acc[m][n] = __builtin_amdgcn_mfma_f32_16x16x32_bf16(af[m], bfr[n], acc[m][n], 0, 0, 0);
  }
}

// Double-buffered K loop (used by k_gemm1, whose grid is exactly 2 blocks/CU
// so extra LDS costs no residency there): stage(t+1) before compute(t).
__device__ __forceinline__ void gemm_dbuf_loop(
    const bf16* __restrict__ a_base, const bf16* __restrict__ b_base,
    const int stride, const int ksteps, const int wave, const int lane,
    bf16* ldsA0, bf16* ldsB0, bf16* ldsA1, bf16* ldsB1, v4f acc[4][4]) {
  stage_tiles(a_base, b_base, stride, 0, wave, lane, ldsA0, ldsB0);
  __syncthreads();
  int cur = 0;
  for (int kt = 0; kt < ksteps - 1; ++kt) {
    if (cur == 0)
      stage_tiles(a_base, b_base, stride, (kt + 1) * 64, wave, lane, ldsA1, ldsB1);
    else
      stage_tiles(a_base, b_base, stride, (kt + 1) * 64, wave, lane, ldsA0, ldsB0);
    compute_tile(cur == 0 ? ldsA0 : ldsA1, cur == 0 ? ldsB0 : ldsB1, wave, lane, acc);
    __syncthreads();
    cur ^= 1;
  }
  compute_tile(cur == 0 ? ldsA0 : ldsA1, cur == 0 ? ldsB0 : ldsB1, wave, lane, acc);
}

// Single-buffered K loop (m97 structure, 32 KiB LDS -> up to 5 blocks/CU):
// stage -> barrier (drains vmcnt) -> compute -> barrier. Latency is hidden by
// inter-block wave overlap, not intra-wave dbuf.
__device__ __forceinline__ void gemm_sbuf_loop(
    const bf16* __restrict__ a_base, const bf16* __restrict__ b_base,
    const int stride, const int ksteps, const int wave, const int lane,
    bf16* ldsA, bf16* ldsB, v4f acc[4][4]) {
  for (int kt = 0; kt < ksteps; ++kt) {
    stage_tiles(a_base, b_base, stride, kt * 64, wave, lane, ldsA, ldsB);
    __syncthreads();
    compute_tile(ldsA, ldsB, wave, lane, acc);
    __syncthreads();
  }
}

// ---------------- pass 1: energy = V V^T (split-K = 2, f32 partials) --------
__global__ __launch_bounds__(256) void k_gemm1(
    const bf16* __restrict__ v, float* __restrict__ e_part) {
  __shared__ __align__(16) bf16 lds[4][128 * 64];  // A0,B0,A1,B1
  int t = blockIdx.x;
  const int ks = t >> 8;
  t &= 255;
  const int b = t >> 4;
  const int cb = (t >> 2) & 3;
  const int db = t & 3;
  const int tid = threadIdx.x;
  const int wave = tid >> 6, lane = tid & 63;
  const bf16* vb = v + (size_t)b * ((size_t)C_DIM * HW_DIM) + ks * (HW_DIM / 2);
  v4f acc[4][4] = {};
  gemm_dbuf_loop(vb + (size_t)(cb * 128) * HW_DIM,
                 vb + (size_t)(db * 128) * HW_DIM,
                 HW_DIM, (HW_DIM / 2) / 64, wave, lane,
                 lds[0], lds[1], lds[2], lds[3], acc);
  float* eb = e_part + (size_t)ks * ((size_t)B_DIM * C_DIM * C_DIM) +
              (size_t)b * (C_DIM * C_DIM);
  const int wr = wave >> 1, wc = wave & 1;
  const int rl = lane & 15;
  const int r0 = (lane >> 4) * 4;
#pragma unroll
  for (int m = 0; m < 4; ++m)
#pragma unroll
    for (int n = 0; n < 4; ++n) {
      const int row0 = cb * 128 + wr * 64 + m * 16 + r0;
      const int col = db * 128 + wc * 64 + n * 16 + rl;
#pragma unroll
      for (int r = 0; r < 4; ++r)
        eb[(size_t)(row0 + r) * C_DIM + col] = acc[m][n][r];
    }
}

// ---------------- pass 2: row softmax (sums 2 partials), write bf16 ---------
__global__ __launch_bounds__(256) void k_softmax(
    const float* __restrict__ e_part, unsigned short* __restrict__ attn) {
  const int row = blockIdx.x;  // 0..8191 = b*512 + c
  const float* e0 = e_part + (size_t)row * C_DIM;
  const float* e1 = e0 + (size_t)B_DIM * C_DIM * C_DIM;
  const int tid = threadIdx.x;
  const float v0 = e0[tid] + e1[tid];
  const float v1 = e0[tid + 256] + e1[tid + 256];
  float mx = fmaxf(v0, v1);
#pragma unroll
  for (int off = 32; off > 0; off >>= 1) mx = fmaxf(mx, __shfl_xor(mx, off));
  __shared__ float rmax[4], rsum[4];
  const int wv = tid >> 6, ln = tid & 63;
  if (ln == 0) rmax[wv] = mx;
  __syncthreads();
  mx = fmaxf(fmaxf(rmax[0], rmax[1]), fmaxf(rmax[2], rmax[3]));
  const float p0 = __expf(v0 - mx), p1 = __expf(v1 - mx);
  float s = p0 + p1;
#pragma unroll
  for (int off = 32; off > 0; off >>= 1) s += __shfl_xor(s, off);
  if (ln == 0) rsum[wv] = s;
  __syncthreads();
  s = rsum[0] + rsum[1] + rsum[2] + rsum[3];
  const float inv = 1.0f / s;
  attn[(size_t)row * C_DIM + tid] = f2bf(p0 * inv);
  attn[(size_t)row * C_DIM + tid + 256] = f2bf(p1 * inv);
}

// ---------------- pass 3: out = gamma*(attn @ V) + V  (f32 to d_out) --------
// Residual read from bf16 V (halves fetch); error ~2^-9 * |v| well under thr.
// Single-buffered (32 KiB LDS): grid = 2048 blocks = 8/CU churn, so residency
// (up to 5 blocks/CU) provides the latency hiding the dbuf used to.
__global__ __launch_bounds__(256) void k_gemm2(
    const bf16* __restrict__ attn, const bf16* __restrict__ vt,
    const unsigned short* __restrict__ vres, const float* __restrict__ gamma,
    float* __restrict__ out) {
  __shared__ __align__(16) bf16 lds[2][128 * 64];  // A,B single buffer
  const int bidx = blockIdx.x;
  const int b = bidx >> 7;
  const int cb = (bidx >> 5) & 3;
  const int nb = bidx & 31;
  const int tid = threadIdx.x;
  const int wave = tid >> 6, lane = tid & 63;
  const bf16* ab = attn + (size_t)b * (C_DIM * C_DIM) + (size_t)(cb * 128) * C_DIM;
  const bf16* bb = vt + (size_t)b * ((size_t)C_DIM * HW_DIM) + (size_t)(nb * 128) * C_DIM;
  v4f acc[4][4] = {};
  gemm_sbuf_loop(ab, bb, C_DIM, C_DIM / 64, wave, lane, lds[0], lds[1], acc);
  const float g = gamma[0];
  const size_t boff = (size_t)b * ((size_t)C_DIM * HW_DIM);
  const unsigned short* xb = vres + boff;
  float* ob = out + boff;
  const int wr = wave >> 1, wc = wave & 1;
  const int rl = lane & 15;
  const int r0 = (lane >> 4) * 4;
#pragma unroll
  for (int m = 0; m < 4; ++m)
#pragma unroll
    for (int n = 0; n < 4; ++n) {
      const int c0 = cb * 128 + wr * 64 + m * 16 + r0;
      const int nn = nb * 128 + wc * 64 + n * 16 + rl;
#pragma unroll
      for (int r = 0; r < 4; ++r) {
        const size_t idx = (size_t)(c0 + r) * HW_DIM + nn;
        ob[idx] = g * acc[m][n][r] + bf2f(xb[idx]);
      }
    }
}

// ---------------- pass 4: in-place LayerNorm over HW=4096 per row -----------
__global__ __launch_bounds__(256) void k_ln(
    float* __restrict__ out, const float* __restrict__ w,
    const float* __restrict__ bias) {
  const int row = blockIdx.x;  // 0..8191
  float* p = out + (size_t)row * HW_DIM;
  const int tid = threadIdx.x;
  float4 vals[4];
  float s = 0.f, ss = 0.f;
#pragma unroll
  for (int i = 0; i < 4; ++i) {
    const float4 vv = ((const float4*)p)[tid + i * 256];
    vals[i] = vv;
    s += vv.x + vv.y + vv.z + vv.w;
    ss += vv.x * vv.x + vv.y * vv.y + vv.z * vv.z + vv.w * vv.w;
  }
#pragma unroll
  for (int off = 32; off > 0; off >>= 1) {
    s += __shfl_xor(s, off);
    ss += __shfl_xor(ss, off);
  }
  __shared__ float rs[4], rss[4];
  const int wv = tid >> 6, ln = tid & 63;
  if (ln == 0) { rs[wv] = s; rss[wv] = ss; }
  __syncthreads();
  s = rs[0] + rs[1] + rs[2] + rs[3];
  ss = rss[0] + rss[1] + rss[2] + rss[3];
  const float mean = s * (1.f / HW_DIM);
  const float var = ss * (1.f / HW_DIM) - mean * mean;
  const float rstd = rsqrtf(var + LN_EPS);
#pragma unroll
  for (int i = 0; i < 4; ++i) {
    const int idx = tid + i * 256;
    const float4 vv = vals[i];
    const float4 w4 = ((const float4*)w)[idx];
    const float4 b4 = ((const float4*)bias)[idx];
    float4 r;
    r.x = (vv.x - mean) * rstd * w4.x + b4.x;
    r.y = (vv.y - mean) * rstd * w4.y + b4.y;
    r.z = (vv.z - mean) * rstd * w4.z + b4.z;
    r.w = (vv.w - mean) * rstd * w4.w + b4.w;
    ((float4*)p)[idx] = r;
  }
}

extern "C" void kernel_launch(void* const* d_in, const int* in_sizes, int n_in,
                              void* d_out, int out_size, void* d_ws, size_t ws_size,
                              hipStream_t stream) {
  const float* x = (const float*)d_in[0];
  const float* gamma = (const float*)d_in[1];
  const float* lnw = (const float*)d_in[2];
  const float* lnb = (const float*)d_in[3];
  float* out = (float*)d_out;
  char* ws = (char*)d_ws;

  const size_t n_elem = (size_t)B_DIM * C_DIM * HW_DIM;       // 33,554,432
  const size_t e_elems = (size_t)B_DIM * C_DIM * C_DIM;       // 4,194,304
  unsigned short* vbf = (unsigned short*)ws;                  // 64 MiB
  unsigned short* vbfT = (unsigned short*)(ws + 2 * n_elem);  // 64 MiB
  float* e_part = (float*)(ws + 4 * n_elem);                  // 2 x 16 MiB
  unsigned short* attn =
      (unsigned short*)(ws + 4 * n_elem + 2 * e_elems * sizeof(float));  // 8 MiB

  k_convert_transpose<<<dim3(HW_DIM / 64, C_DIM / 64, B_DIM), 256, 0, stream>>>(
      x, vbf, vbfT);
  k_gemm1<<<512, 256, 0, stream>>>((const bf16*)vbf, e_part);
  k_softmax<<<B_DIM * C_DIM, 256, 0, stream>>>(e_part, attn);
  k_gemm2<<<B_DIM * 128, 256, 0, stream>>>((const bf16*)attn, (const bf16*)vbfT,
                                           vbf, gamma, out);
  k_ln<<<B_DIM * C_DIM, 256, 0, stream>>>(out, lnw, lnb);
}

// Round 2
// 231.013 us; speedup vs baseline: 1.0856x; 1.0856x over previous
//
#include <hip/hip_runtime.h>
#include <hip/hip_bf16.h>

#define B_DIM 16
#define C_DIM 512
#define HW_DIM 4096
#define LN_EPS 1e-5f

using bf16 = __hip_bfloat16;
typedef __bf16 v8bf __attribute__((ext_vector_type(8)));
typedef float v4f __attribute__((ext_vector_type(4)));
typedef unsigned short v8us __attribute__((ext_vector_type(8)));
using gptr_t = const __attribute__((address_space(1))) void*;
using lptr_t = __attribute__((address_space(3))) void*;

__device__ __forceinline__ unsigned short f2bf(float f) {
  unsigned int u = __float_as_uint(f);
  u = (u + 0x7fffu + ((u >> 16) & 1u)) >> 16;  // RNE
  return (unsigned short)u;
}
__device__ __forceinline__ float bf2f(unsigned short us) {
  return __uint_as_float(((unsigned int)us) << 16);
}

// ---------------- pass 0: f32 -> bf16 (V) and bf16 transposed (VT) ----------
__global__ __launch_bounds__(256) void k_convert_transpose(
    const float* __restrict__ x, unsigned short* __restrict__ v,
    unsigned short* __restrict__ vt) {
  __shared__ unsigned short tile[64][66];  // [c][hw], pad 66
  const int tid = threadIdx.x;
  const int b = blockIdx.z;
  const int n0 = blockIdx.x * 64;
  const int c0 = blockIdx.y * 64;
  const size_t boff = (size_t)b * ((size_t)C_DIM * HW_DIM);
  const float* xb = x + boff;
  unsigned short* vb = v + boff;
  unsigned short* vtb = vt + boff;

  const int cl = tid >> 3;           // 0..31
  const int h8 = (tid & 7) * 8;      // 0,8,..56
#pragma unroll
  for (int j = 0; j < 2; ++j) {
    const int c = cl + j * 32;
    const float* src = xb + (size_t)(c0 + c) * HW_DIM + n0 + h8;
    const float4 f0 = ((const float4*)src)[0];
    const float4 f1 = ((const float4*)src)[1];
    v8us pack;
    pack[0] = f2bf(f0.x); pack[1] = f2bf(f0.y);
    pack[2] = f2bf(f0.z); pack[3] = f2bf(f0.w);
    pack[4] = f2bf(f1.x); pack[5] = f2bf(f1.y);
    pack[6] = f2bf(f1.z); pack[7] = f2bf(f1.w);
    *(v8us*)(vb + (size_t)(c0 + c) * HW_DIM + n0 + h8) = pack;
#pragma unroll
    for (int e = 0; e < 8; ++e) tile[c][h8 + e] = pack[e];
  }
  __syncthreads();
  const int nl = tid >> 3;           // 0..31
  const int c8 = (tid & 7) * 8;      // 0,8,..56
#pragma unroll
  for (int j = 0; j < 2; ++j) {
    const int n = nl + j * 32;
    v8us pack;
#pragma unroll
    for (int e = 0; e < 8; ++e) pack[e] = tile[c8 + e][n];
    *(v8us*)(vtb + (size_t)(n0 + n) * C_DIM + c0 + c8) = pack;
  }
}

// ---------------- gemm1 pieces (dbuf 128x128, unchanged) --------------------
__device__ __forceinline__ void stage_tiles(
    const bf16* __restrict__ a_base, const bf16* __restrict__ b_base,
    const int stride, const int k0, const int wave, const int lane,
    bf16* ldsA, bf16* ldsB) {
  const int srow = lane >> 3;        // 0..7
  const int skcol = (lane & 7) * 8;  // 0..56
#pragma unroll
  for (int i = 0; i < 4; ++i) {
    const int ci = wave * 4 + i;     // chunk of 8 rows
    const int row = ci * 8 + srow;
    __builtin_amdgcn_global_load_lds(
        (gptr_t)(a_base + (size_t)row * stride + k0 + skcol),
        (lptr_t)(ldsA + ci * 512), 16, 0, 0);
    __builtin_amdgcn_global_load_lds(
        (gptr_t)(b_base + (size_t)row * stride + k0 + skcol),
        (lptr_t)(ldsB + ci * 512), 16, 0, 0);
  }
}

__device__ __forceinline__ void compute_tile(
    const bf16* ldsA, const bf16* ldsB, const int wave, const int lane,
    v4f acc[4][4]) {
  const int kb = (lane >> 4) * 8;
  const int rl = lane & 15;
  const int wr = wave >> 1, wc = wave & 1;
#pragma unroll
  for (int kk = 0; kk < 2; ++kk) {
    v8bf af[4], bfr[4];
#pragma unroll
    for (int m = 0; m < 4; ++m)
      af[m] = *(const v8bf*)(ldsA + (wr * 64 + m * 16 + rl) * 64 + kk * 32 + kb);
#pragma unroll
    for (int n = 0; n < 4; ++n)
      bfr[n] = *(const v8bf*)(ldsB + (wc * 64 + n * 16 + rl) * 64 + kk * 32 + kb);
#pragma unroll
    for (int m = 0; m < 4; ++m)
#pragma unroll
      for (int n = 0; n < 4; ++n)
        acc[m][n] = __builtin_amdgcn_mfma_f32_16x16x32_bf16(af[m], bfr[n], acc[m][n], 0, 0, 0);
  }
}

__device__ __forceinline__ void gemm_dbuf_loop(
    const bf16* __restrict__ a_base, const bf16* __restrict__ b_base,
    const int stride, const int ksteps, const int wave, const int lane,
    bf16* ldsA0, bf16* ldsB0, bf16* ldsA1, bf16* ldsB1, v4f acc[4][4]) {
  stage_tiles(a_base, b_base, stride, 0, wave, lane, ldsA0, ldsB0);
  __syncthreads();
  int cur = 0;
  for (int kt = 0; kt < ksteps - 1; ++kt) {
    if (cur == 0)
      stage_tiles(a_base, b_base, stride, (kt + 1) * 64, wave, lane, ldsA1, ldsB1);
    else
      stage_tiles(a_base, b_base, stride, (kt + 1) * 64, wave, lane, ldsA0, ldsB0);
    compute_tile(cur == 0 ? ldsA0 : ldsA1, cur == 0 ? ldsB0 : ldsB1, wave, lane, acc);
    __syncthreads();
    cur ^= 1;
  }
  compute_tile(cur == 0 ? ldsA0 : ldsA1, cur == 0 ? ldsB0 : ldsB1, wave, lane, acc);
}

// ---------------- pass 1: energy = V V^T (split-K = 2, f32 partials) --------
__global__ __launch_bounds__(256) void k_gemm1(
    const bf16* __restrict__ v, float* __restrict__ e_part) {
  __shared__ __align__(16) bf16 lds[4][128 * 64];  // A0,B0,A1,B1
  int t = blockIdx.x;
  const int ks = t >> 8;
  t &= 255;
  const int b = t >> 4;
  const int cb = (t >> 2) & 3;
  const int db = t & 3;
  const int tid = threadIdx.x;
  const int wave = tid >> 6, lane = tid & 63;
  const bf16* vb = v + (size_t)b * ((size_t)C_DIM * HW_DIM) + ks * (HW_DIM / 2);
  v4f acc[4][4] = {};
  gemm_dbuf_loop(vb + (size_t)(cb * 128) * HW_DIM,
                 vb + (size_t)(db * 128) * HW_DIM,
                 HW_DIM, (HW_DIM / 2) / 64, wave, lane,
                 lds[0], lds[1], lds[2], lds[3], acc);
  float* eb = e_part + (size_t)ks * ((size_t)B_DIM * C_DIM * C_DIM) +
              (size_t)b * (C_DIM * C_DIM);
  const int wr = wave >> 1, wc = wave & 1;
  const int rl = lane & 15;
  const int r0 = (lane >> 4) * 4;
#pragma unroll
  for (int m = 0; m < 4; ++m)
#pragma unroll
    for (int n = 0; n < 4; ++n) {
      const int row0 = cb * 128 + wr * 64 + m * 16 + r0;
      const int col = db * 128 + wc * 64 + n * 16 + rl;
#pragma unroll
      for (int r = 0; r < 4; ++r)
        eb[(size_t)(row0 + r) * C_DIM + col] = acc[m][n][r];
    }
}

// ---------------- pass 2: row softmax (sums 2 partials), write bf16 ---------
__global__ __launch_bounds__(256) void k_softmax(
    const float* __restrict__ e_part, unsigned short* __restrict__ attn) {
  const int row = blockIdx.x;  // 0..8191 = b*512 + c
  const float* e0 = e_part + (size_t)row * C_DIM;
  const float* e1 = e0 + (size_t)B_DIM * C_DIM * C_DIM;
  const int tid = threadIdx.x;
  const float v0 = e0[tid] + e1[tid];
  const float v1 = e0[tid + 256] + e1[tid + 256];
  float mx = fmaxf(v0, v1);
#pragma unroll
  for (int off = 32; off > 0; off >>= 1) mx = fmaxf(mx, __shfl_xor(mx, off));
  __shared__ float rmax[4], rsum[4];
  const int wv = tid >> 6, ln = tid & 63;
  if (ln == 0) rmax[wv] = mx;
  __syncthreads();
  mx = fmaxf(fmaxf(rmax[0], rmax[1]), fmaxf(rmax[2], rmax[3]));
  const float p0 = __expf(v0 - mx), p1 = __expf(v1 - mx);
  float s = p0 + p1;
#pragma unroll
  for (int off = 32; off > 0; off >>= 1) s += __shfl_xor(s, off);
  if (ln == 0) rsum[wv] = s;
  __syncthreads();
  s = rsum[0] + rsum[1] + rsum[2] + rsum[3];
  const float inv = 1.0f / s;
  attn[(size_t)row * C_DIM + tid] = f2bf(p0 * inv);
  attn[(size_t)row * C_DIM + tid + 256] = f2bf(p1 * inv);
}

// ---------------- pass 3: 256x256-tile 8-wave 8-phase GEMM ------------------
// out = gamma*(attn @ V) + V.  A = attn rows (k=d), B = VT rows (k=d), both
// stride C_DIM.  BK=64, 8 K-tiles.  2 LDS buffers (128 KiB total), counted
// vmcnt(8) per K-tile boundary (never 0 mid-loop).  LDS XOR-swizzle
// (chunk ^= row&7) applied on pre-swizzled global source + ds_read address.
#define TILE_E (256 * 64)

__device__ __forceinline__ void stage_half8(
    const bf16* __restrict__ g, bf16* l, int k0, int wave, int lane) {
  const int lrow = lane >> 3, lc = lane & 7;
#pragma unroll
  for (int i = 0; i < 2; ++i) {
    const int row = i * 64 + wave * 8 + lrow;
    __builtin_amdgcn_global_load_lds(
        (gptr_t)(g + (size_t)row * C_DIM + k0 + ((lc ^ (row & 7)) << 3)),
        (lptr_t)(l + (i * 64 + wave * 8) * 64), 16, 0, 0);
  }
}
__device__ __forceinline__ void stage_op2(
    const bf16* __restrict__ g, bf16* l, int k0, int wave, int lane) {
  stage_half8(g, l, k0, wave, lane);
  stage_half8(g + (size_t)128 * C_DIM, l + 128 * 64, k0, wave, lane);
}
__device__ __forceinline__ v8bf ld_frag8(const bf16* l, int row, int j) {
  return *(const v8bf*)(l + row * 64 + ((j ^ (row & 7)) << 3));
}

__global__ __launch_bounds__(512, 2) void k_gemm2(
    const bf16* __restrict__ attn, const bf16* __restrict__ vt,
    const unsigned short* __restrict__ vres, const float* __restrict__ gamma,
    float* __restrict__ out) {
  __shared__ __align__(16) bf16 smA[2][TILE_E];  // 64 KiB
  __shared__ __align__(16) bf16 smB[2][TILE_E];  // 64 KiB
  const int bid = blockIdx.x;
  // XCD-chunked bijective swizzle (512 % 8 == 0): XCD x gets batches 2x,2x+1
  const int t = (bid & 7) * 64 + (bid >> 3);
  const int b = t >> 5;
  const int cb = (t >> 4) & 1;
  const int nb = t & 15;
  const int tid = threadIdx.x;
  const int wave = tid >> 6, lane = tid & 63;
  const int wm = wave >> 2, wn = wave & 3;  // 2M x 4N waves, 128x64 each
  const int rl = lane & 15, kq = lane >> 4;

  const bf16* Ab = attn + (size_t)b * (C_DIM * C_DIM) + (size_t)(cb * 256) * C_DIM;
  const bf16* Bb = vt + (size_t)b * ((size_t)C_DIM * HW_DIM) + (size_t)(nb * 256) * C_DIM;

  v4f acc[8][4] = {};

  // prologue: stage tiles 0 and 1 fully (order per tile: B then A)
  stage_op2(Bb, smB[0], 0, wave, lane);
  stage_op2(Ab, smA[0], 0, wave, lane);
  stage_op2(Bb, smB[1], 64, wave, lane);
  stage_op2(Ab, smA[1], 64, wave, lane);
  asm volatile("s_waitcnt vmcnt(8)" ::: "memory");  // tile 0 landed
  __builtin_amdgcn_s_barrier();

  v8bf a[4][2], b01[2][2], b23[2][2];
  for (int kt = 0; kt < 8; ++kt) {
    const bf16* LA = smA[kt & 1];
    const bf16* LB = smB[kt & 1];
    // ---- ph0: read A m0-3 + B n0-1 (12 ds_read_b128); MFMA q0 ----
#pragma unroll
    for (int mi = 0; mi < 4; ++mi)
#pragma unroll
      for (int kk = 0; kk < 2; ++kk)
        a[mi][kk] = ld_frag8(LA, wm * 128 + mi * 16 + rl, kk * 4 + kq);
#pragma unroll
    for (int ni = 0; ni < 2; ++ni)
#pragma unroll
      for (int kk = 0; kk < 2; ++kk)
        b01[ni][kk] = ld_frag8(LB, wn * 64 + ni * 16 + rl, kk * 4 + kq);
    __builtin_amdgcn_s_barrier();
    asm volatile("s_waitcnt lgkmcnt(0)");
    __builtin_amdgcn_s_setprio(1);
#pragma unroll
    for (int kk = 0; kk < 2; ++kk)
#pragma unroll
      for (int mi = 0; mi < 4; ++mi)
#pragma unroll
        for (int ni = 0; ni < 2; ++ni)
          acc[mi][ni] = __builtin_amdgcn_mfma_f32_16x16x32_bf16(
              a[mi][kk], b01[ni][kk], acc[mi][ni], 0, 0, 0);
    __builtin_amdgcn_s_setprio(0);
    __builtin_amdgcn_s_barrier();
    // ---- ph1: read B n2-3 (4); MFMA q1 ----
#pragma unroll
    for (int ni = 0; ni < 2; ++ni)
#pragma unroll
      for (int kk = 0; kk < 2; ++kk)
        b23[ni][kk] = ld_frag8(LB, wn * 64 + (ni + 2) * 16 + rl, kk * 4 + kq);
    __builtin_amdgcn_s_barrier();
    asm volatile("s_waitcnt lgkmcnt(0)");
    __builtin_amdgcn_s_setprio(1);
#pragma unroll
    for (int kk = 0; kk < 2; ++kk)
#pragma unroll
      for (int mi = 0; mi < 4; ++mi)
#pragma unroll
        for (int ni = 0; ni < 2; ++ni)
          acc[mi][ni + 2] = __builtin_amdgcn_mfma_f32_16x16x32_bf16(
              a[mi][kk], b23[ni][kk], acc[mi][ni + 2], 0, 0, 0);
    __builtin_amdgcn_s_setprio(0);
    __builtin_amdgcn_s_barrier();
    // ---- ph2: read A m4-7 (8); stage B(kt+2) [B rows dead after ph1 bar];
    //           MFMA q2 ----
#pragma unroll
    for (int mi = 0; mi < 4; ++mi)
#pragma unroll
      for (int kk = 0; kk < 2; ++kk)
        a[mi][kk] = ld_frag8(LA, wm * 128 + (mi + 4) * 16 + rl, kk * 4 + kq);
    if (kt < 6) stage_op2(Bb, smB[kt & 1], (kt + 2) * 64, wave, lane);
    __builtin_amdgcn_s_barrier();
    asm volatile("s_waitcnt lgkmcnt(0)");
    __builtin_amdgcn_s_setprio(1);
#pragma unroll
    for (int kk = 0; kk < 2; ++kk)
#pragma unroll
      for (int mi = 0; mi < 4; ++mi)
#pragma unroll
        for (int ni = 0; ni < 2; ++ni)
          acc[mi + 4][ni + 2] = __builtin_amdgcn_mfma_f32_16x16x32_bf16(
              a[mi][kk], b23[ni][kk], acc[mi + 4][ni + 2], 0, 0, 0);
    __builtin_amdgcn_s_setprio(0);
    __builtin_amdgcn_s_barrier();
    // ---- ph3: stage A(kt+2) [A rows dead after ph2 bar]; MFMA q3;
    //           counted vmcnt at K-tile boundary ----
    if (kt < 6) stage_op2(Ab, smA[kt & 1], (kt + 2) * 64, wave, lane);
    __builtin_amdgcn_s_barrier();
    __builtin_amdgcn_s_setprio(1);
#pragma unroll
    for (int kk = 0; kk < 2; ++kk)
#pragma unroll
      for (int mi = 0; mi < 4; ++mi)
#pragma unroll
        for (int ni = 0; ni < 2; ++ni)
          acc[mi + 4][ni] = __builtin_amdgcn_mfma_f32_16x16x32_bf16(
              a[mi][kk], b01[ni][kk], acc[mi + 4][ni], 0, 0, 0);
    __builtin_amdgcn_s_setprio(0);
    if (kt < 6)
      asm volatile("s_waitcnt vmcnt(8)" ::: "memory");   // tile kt+1 landed
    else if (kt == 6)
      asm volatile("s_waitcnt vmcnt(0)" ::: "memory");   // tile 7 landed
    __builtin_amdgcn_s_barrier();
  }

  // epilogue: out = gamma*acc + residual (bf16 V)
  const float g = gamma[0];
  const size_t boff = (size_t)b * ((size_t)C_DIM * HW_DIM);
  const unsigned short* xb = vres + boff;
  float* ob = out + boff;
  const int r0 = kq * 4;
#pragma unroll
  for (int mi = 0; mi < 8; ++mi)
#pragma unroll
    for (int ni = 0; ni < 4; ++ni) {
      const int c0 = cb * 256 + wm * 128 + mi * 16 + r0;
      const int nn = nb * 256 + wn * 64 + ni * 16 + rl;
#pragma unroll
      for (int r = 0; r < 4; ++r) {
        const size_t idx = (size_t)(c0 + r) * HW_DIM + nn;
        ob[idx] = g * acc[mi][ni][r] + bf2f(xb[idx]);
      }
    }
}

// ---------------- pass 4: in-place LayerNorm over HW=4096 per row -----------
__global__ __launch_bounds__(256) void k_ln(
    float* __restrict__ out, const float* __restrict__ w,
    const float* __restrict__ bias) {
  const int row = blockIdx.x;  // 0..8191
  float* p = out + (size_t)row * HW_DIM;
  const int tid = threadIdx.x;
  float4 vals[4];
  float s = 0.f, ss = 0.f;
#pragma unroll
  for (int i = 0; i < 4; ++i) {
    const float4 vv = ((const float4*)p)[tid + i * 256];
    vals[i] = vv;
    s += vv.x + vv.y + vv.z + vv.w;
    ss += vv.x * vv.x + vv.y * vv.y + vv.z * vv.z + vv.w * vv.w;
  }
#pragma unroll
  for (int off = 32; off > 0; off >>= 1) {
    s += __shfl_xor(s, off);
    ss += __shfl_xor(ss, off);
  }
  __shared__ float rs[4], rss[4];
  const int wv = tid >> 6, ln = tid & 63;
  if (ln == 0) { rs[wv] = s; rss[wv] = ss; }
  __syncthreads();
  s = rs[0] + rs[1] + rs[2] + rs[3];
  ss = rss[0] + rss[1] + rss[2] + rss[3];
  const float mean = s * (1.f / HW_DIM);
  const float var = ss * (1.f / HW_DIM) - mean * mean;
  const float rstd = rsqrtf(var + LN_EPS);
#pragma unroll
  for (int i = 0; i < 4; ++i) {
    const int idx = tid + i * 256;
    const float4 vv = vals[i];
    const float4 w4 = ((const float4*)w)[idx];
    const float4 b4 = ((const float4*)bias)[idx];
    float4 r;
    r.x = (vv.x - mean) * rstd * w4.x + b4.x;
    r.y = (vv.y - mean) * rstd * w4.y + b4.y;
    r.z = (vv.z - mean) * rstd * w4.z + b4.z;
    r.w = (vv.w - mean) * rstd * w4.w + b4.w;
    ((float4*)p)[idx] = r;
  }
}

extern "C" void kernel_launch(void* const* d_in, const int* in_sizes, int n_in,
                              void* d_out, int out_size, void* d_ws, size_t ws_size,
                              hipStream_t stream) {
  const float* x = (const float*)d_in[0];
  const float* gamma = (const float*)d_in[1];
  const float* lnw = (const float*)d_in[2];
  const float* lnb = (const float*)d_in[3];
  float* out = (float*)d_out;
  char* ws = (char*)d_ws;

  const size_t n_elem = (size_t)B_DIM * C_DIM * HW_DIM;       // 33,554,432
  const size_t e_elems = (size_t)B_DIM * C_DIM * C_DIM;       // 4,194,304
  unsigned short* vbf = (unsigned short*)ws;                  // 64 MiB
  unsigned short* vbfT = (unsigned short*)(ws + 2 * n_elem);  // 64 MiB
  float* e_part = (float*)(ws + 4 * n_elem);                  // 2 x 16 MiB
  unsigned short* attn =
      (unsigned short*)(ws + 4 * n_elem + 2 * e_elems * sizeof(float));  // 8 MiB

  k_convert_transpose<<<dim3(HW_DIM / 64, C_DIM / 64, B_DIM), 256, 0, stream>>>(
      x, vbf, vbfT);
  k_gemm1<<<512, 256, 0, stream>>>((const bf16*)vbf, e_part);
  k_softmax<<<B_DIM * C_DIM, 256, 0, stream>>>(e_part, attn);
  k_gemm2<<<512, 512, 0, stream>>>((const bf16*)attn, (const bf16*)vbfT,
                                   vbf, gamma, out);
  k_ln<<<B_DIM * C_DIM, 256, 0, stream>>>(out, lnw, lnb);
}